// Round 9
// baseline (241.995 us; speedup 1.0000x reference)
//
#include <hip/hip_runtime.h>
#include <hip/hip_bf16.h>

// SimVQ: z[16,1024,64] f32, codebook[16384,64] f32, proj_w[64,64] f32, proj_b[64] f32, scale f32
// Outputs (fp32, concat): quantized_st[1048576], vq_loss[1], idx[16384]
// r9: (1) projection via hi/lo (Ozaki) bf16 MFMA -> fp32-accurate qcb/cnb, no fp64 LDS GEMM;
// (2) GEMM passes at 8 blocks/CU (16 splits, 64-code dbuf stages, 16KB LDS); (3) fused
// k_final = exact-arbiter + overflow + gather/out (block-local token resolution). 4 launches.
// Margin scheme proven r5-r8: pass1 mfma top value, pass2 collect within 8e-3
// (quant err <= 4e-3 + proj err ~1e-5), fp64 arbiter recomputes qc from cb/W exactly.

#define NCODES 16384
#define NTOK   16384
#define DIM    64
#define MARGIN_MFMA 8e-3f
#define CAP    16

typedef __attribute__((ext_vector_type(8))) short bf16x8;
typedef __attribute__((ext_vector_type(4))) float f32x4;
#define GLOBAL_AS __attribute__((address_space(1)))
#define LDS_AS    __attribute__((address_space(3)))

__device__ float  g_qcb[NCODES * DIM];   // 4 MB projected codebook fp32 (gather source)
__device__ short  g_cnb[NCODES * DIM];   // 2 MB l2norm(qcb) bf16 row-major (MFMA B)
__device__ short  g_znb[NTOK * DIM];     // 2 MB l2norm(z)  bf16 row-major (MFMA A)
__device__ unsigned g_topu[NTOK];        // orderable-encoded mfma top-1 value
__device__ int    g_candcnt[NTOK];
__device__ int    g_cand[NTOK * CAP];    // 1 MB
__device__ float  g_loss;
__device__ int    g_done;

__device__ __forceinline__ float wave_sum64(float v) {
#pragma unroll
  for (int o = 32; o > 0; o >>= 1) v += __shfl_xor(v, o, 64);
  return v;
}
__device__ __forceinline__ double wave_sum64d(double v) {
#pragma unroll
  for (int o = 32; o > 0; o >>= 1) v += __shfl_xor(v, o, 64);
  return v;
}
__device__ __forceinline__ short f2bf(float f) {
  __hip_bfloat16 h = __float2bfloat16(f);
  return *reinterpret_cast<short*>(&h);
}
__device__ __forceinline__ float bf2f(short s) {
  __hip_bfloat16 h = *reinterpret_cast<__hip_bfloat16*>(&s);
  return __bfloat162float(h);
}
// split 8 consecutive floats into bf16 hi + bf16 residual lo
__device__ __forceinline__ void split8(const float* v, bf16x8& hi, bf16x8& lo) {
#pragma unroll
  for (int i = 0; i < 8; ++i) {
    float f = v[i];
    short h = f2bf(f);
    hi[i] = h;
    lo[i] = f2bf(f - bf2f(h));
  }
}

// k_prep: blocks [0,256): projection qc = cb@W^T + b via Ozaki hi/lo bf16 MFMA (fp32-class
// accuracy) -> fp32 qcb, bf16 cnb. blocks [256,512): znorm -> bf16 znb + zero per-call state.
// MFMA layouts (HW-proven r5-r8): A m=col,k=quad*8+i ; B n=col,k=quad*8+i ; C/D m=quad*4+r,n=col.
__global__ __launch_bounds__(256) void k_prep(const float* __restrict__ cb,
                                              const float* __restrict__ pw,
                                              const float* __restrict__ pb,
                                              const float* __restrict__ z) {
  int tid = threadIdx.x;
  int wave = tid >> 6, lane = tid & 63, quad = lane >> 4, col = lane & 15;
  if (blockIdx.x < 256) {
    int rowBase = blockIdx.x * 64 + wave * 16;
    const float* cr = cb + (size_t)(rowBase + col) * 64 + quad * 8;
    bf16x8 ah0, al0, ah1, al1;
    split8(cr, ah0, al0);
    split8(cr + 32, ah1, al1);
    float vals[4][4];
    float nr[4] = {0.f, 0.f, 0.f, 0.f};
    const f32x4 fz = {0.f, 0.f, 0.f, 0.f};
#pragma unroll
    for (int nt = 0; nt < 4; ++nt) {
      int j = col + 16 * nt;
      const float* wr = pw + (size_t)j * 64 + quad * 8;
      bf16x8 bh0, bl0, bh1, bl1;
      split8(wr, bh0, bl0);
      split8(wr + 32, bh1, bl1);
      f32x4 d = __builtin_amdgcn_mfma_f32_16x16x32_bf16(ah0, bh0, fz, 0, 0, 0);
      d = __builtin_amdgcn_mfma_f32_16x16x32_bf16(ah1, bh1, d, 0, 0, 0);
      d = __builtin_amdgcn_mfma_f32_16x16x32_bf16(ah0, bl0, d, 0, 0, 0);
      d = __builtin_amdgcn_mfma_f32_16x16x32_bf16(ah1, bl1, d, 0, 0, 0);
      d = __builtin_amdgcn_mfma_f32_16x16x32_bf16(al0, bh0, d, 0, 0, 0);
      d = __builtin_amdgcn_mfma_f32_16x16x32_bf16(al1, bh1, d, 0, 0, 0);
      float bj = pb[j];
#pragma unroll
      for (int r = 0; r < 4; ++r) {
        float v = d[r] + bj;
        vals[nt][r] = v;
        nr[r] = fmaf(v, v, nr[r]);
      }
    }
#pragma unroll
    for (int r = 0; r < 4; ++r) {  // reduce over the 16 col lanes (xor bits 0..3 stay in-quad)
      float v = nr[r];
      v += __shfl_xor(v, 1, 64);
      v += __shfl_xor(v, 2, 64);
      v += __shfl_xor(v, 4, 64);
      v += __shfl_xor(v, 8, 64);
      nr[r] = 1.0f / fmaxf(sqrtf(v), 1e-12f);
    }
#pragma unroll
    for (int nt = 0; nt < 4; ++nt)
#pragma unroll
      for (int r = 0; r < 4; ++r) {
        int row = rowBase + quad * 4 + r;
        int j = col + 16 * nt;
        g_qcb[(size_t)row * 64 + j] = vals[nt][r];
        g_cnb[(size_t)row * 64 + j] = f2bf(vals[nt][r] * nr[r]);
      }
  } else {
    int zb = blockIdx.x - 256;
    int gid = zb * 256 + tid;
    if (gid < NTOK) { g_topu[gid] = 0u; g_candcnt[gid] = 0; }
    if (gid == 0) { g_loss = 0.f; g_done = 0; }
    int w = wave, j = lane;
    int base = zb * 64;
    for (int r = 0; r < 16; ++r) {
      int row = base + w * 16 + r;
      float v = z[(size_t)row * 64 + j];
      float tot = wave_sum64(v * v);
      g_znb[(size_t)row * 64 + j] = f2bf(v / fmaxf(sqrtf(tot), 1e-12f));
    }
  }
}

// GEMM core: grid = 128 tokBlocks x 16 splits = 2048 blocks (8/CU, 16KB LDS), 4 waves/block.
// Wave owns 32 tokens (2 A-frag pairs). B double-buffered 64-code (8KB) stages via
// global_load_lds width-16, XOR-swizzled; ONE barrier/stage (prefetch s+1 before compute s).
__global__ __launch_bounds__(256) void k_mfma1() {
  __shared__ __align__(16) short smB[2][4096];  // 2 x 8 KB: 64 codes x 64 shorts
  int tid = threadIdx.x;
  int wave = tid >> 6, lane = tid & 63;
  int quad = lane >> 4, col = lane & 15;
  int tokBlock = blockIdx.x >> 4, split = blockIdx.x & 15;
  int tokBase = tokBlock * 128 + wave * 32;

  const short* za = g_znb + (size_t)(tokBase + col) * 64 + quad * 8;
  bf16x8 A0[2], A1[2];
#pragma unroll
  for (int f = 0; f < 2; ++f) {
    A0[f] = *(const bf16x8*)(za + f * 16 * 64);
    A1[f] = *(const bf16x8*)(za + f * 16 * 64 + 32);
  }
  float m[2][4];
#pragma unroll
  for (int f = 0; f < 2; ++f)
#pragma unroll
    for (int r = 0; r < 4; ++r) m[f][r] = -3.0e38f;

  const char* gsplit = (const char*)(g_cnb + (size_t)split * 1024 * 64);
  int x = col & 7;
  int s0off = ((quad ^ x) << 3);
  int s1off = (((4 | quad) ^ x) << 3);
  int goff[2];
#pragma unroll
  for (int i = 0; i < 2; ++i) {
    int cidx = wave * 128 + i * 64 + lane;
    int row = cidx >> 3, sw = cidx & 7;
    goff[i] = row * 128 + ((sw ^ (row & 7)) << 4);
  }
  const f32x4 fz = {0.f, 0.f, 0.f, 0.f};

#pragma unroll
  for (int i = 0; i < 2; ++i)
    __builtin_amdgcn_global_load_lds((const GLOBAL_AS void*)(gsplit + goff[i]),
                                     (LDS_AS void*)(&smB[0][wave * 1024 + i * 512]), 16, 0, 0);
  __syncthreads();

  int p = 0;
  for (int s = 0; s < 16; ++s) {
    if (s < 15) {
      const char* gb = gsplit + (size_t)(s + 1) * 8192;
#pragma unroll
      for (int i = 0; i < 2; ++i)
        __builtin_amdgcn_global_load_lds((const GLOBAL_AS void*)(gb + goff[i]),
                                         (LDS_AS void*)(&smB[p ^ 1][wave * 1024 + i * 512]),
                                         16, 0, 0);
    }
    const short* bufp = smB[p];
#pragma unroll
    for (int t = 0; t < 4; ++t) {
      const short* lb = bufp + (t * 16 + col) * 64;
      bf16x8 b0 = *(const bf16x8*)(lb + s0off);
      bf16x8 b1 = *(const bf16x8*)(lb + s1off);
#pragma unroll
      for (int f = 0; f < 2; ++f) {
        f32x4 acc = __builtin_amdgcn_mfma_f32_16x16x32_bf16(A0[f], b0, fz, 0, 0, 0);
        acc = __builtin_amdgcn_mfma_f32_16x16x32_bf16(A1[f], b1, acc, 0, 0, 0);
#pragma unroll
        for (int r = 0; r < 4; ++r) m[f][r] = fmaxf(m[f][r], acc[r]);
      }
    }
    __syncthreads();
    p ^= 1;
  }

#pragma unroll
  for (int f = 0; f < 2; ++f)
#pragma unroll
    for (int r = 0; r < 4; ++r) {
      float v = m[f][r];
      v = fmaxf(v, __shfl_xor(v, 1, 64));
      v = fmaxf(v, __shfl_xor(v, 2, 64));
      v = fmaxf(v, __shfl_xor(v, 4, 64));
      v = fmaxf(v, __shfl_xor(v, 8, 64));
      if (col == 0) {
        unsigned b = __float_as_uint(v);
        unsigned e = (b & 0x80000000u) ? ~b : (b | 0x80000000u);
        atomicMax(&g_topu[tokBase + f * 16 + quad * 4 + r], e);
      }
    }
}

__global__ __launch_bounds__(256) void k_mfma2() {
  __shared__ __align__(16) short smB[2][4096];
  int tid = threadIdx.x;
  int wave = tid >> 6, lane = tid & 63;
  int quad = lane >> 4, col = lane & 15;
  int tokBlock = blockIdx.x >> 4, split = blockIdx.x & 15;
  int tokBase = tokBlock * 128 + wave * 32;

  const short* za = g_znb + (size_t)(tokBase + col) * 64 + quad * 8;
  bf16x8 A0[2], A1[2];
#pragma unroll
  for (int f = 0; f < 2; ++f) {
    A0[f] = *(const bf16x8*)(za + f * 16 * 64);
    A1[f] = *(const bf16x8*)(za + f * 16 * 64 + 32);
  }
  float th[2][4];
#pragma unroll
  for (int f = 0; f < 2; ++f)
#pragma unroll
    for (int r = 0; r < 4; ++r) {
      unsigned u = g_topu[tokBase + f * 16 + quad * 4 + r];
      unsigned b = (u & 0x80000000u) ? (u & 0x7FFFFFFFu) : ~u;
      th[f][r] = __uint_as_float(b) - MARGIN_MFMA;
    }

  const char* gsplit = (const char*)(g_cnb + (size_t)split * 1024 * 64);
  int x = col & 7;
  int s0off = ((quad ^ x) << 3);
  int s1off = (((4 | quad) ^ x) << 3);
  int goff[2];
#pragma unroll
  for (int i = 0; i < 2; ++i) {
    int cidx = wave * 128 + i * 64 + lane;
    int row = cidx >> 3, sw = cidx & 7;
    goff[i] = row * 128 + ((sw ^ (row & 7)) << 4);
  }
  const f32x4 fz = {0.f, 0.f, 0.f, 0.f};

#pragma unroll
  for (int i = 0; i < 2; ++i)
    __builtin_amdgcn_global_load_lds((const GLOBAL_AS void*)(gsplit + goff[i]),
                                     (LDS_AS void*)(&smB[0][wave * 1024 + i * 512]), 16, 0, 0);
  __syncthreads();

  int codeB = split * 1024 + col;
  int p = 0;
  for (int s = 0; s < 16; ++s) {
    if (s < 15) {
      const char* gb = gsplit + (size_t)(s + 1) * 8192;
#pragma unroll
      for (int i = 0; i < 2; ++i)
        __builtin_amdgcn_global_load_lds((const GLOBAL_AS void*)(gb + goff[i]),
                                         (LDS_AS void*)(&smB[p ^ 1][wave * 1024 + i * 512]),
                                         16, 0, 0);
    }
    const short* bufp = smB[p];
#pragma unroll
    for (int t = 0; t < 4; ++t) {
      const short* lb = bufp + (t * 16 + col) * 64;
      bf16x8 b0 = *(const bf16x8*)(lb + s0off);
      bf16x8 b1 = *(const bf16x8*)(lb + s1off);
      int code = codeB + s * 64 + t * 16;
#pragma unroll
      for (int f = 0; f < 2; ++f) {
        f32x4 acc = __builtin_amdgcn_mfma_f32_16x16x32_bf16(A0[f], b0, fz, 0, 0, 0);
        acc = __builtin_amdgcn_mfma_f32_16x16x32_bf16(A1[f], b1, acc, 0, 0, 0);
        float dmax = fmaxf(fmaxf(acc[0] - th[f][0], acc[1] - th[f][1]),
                           fmaxf(acc[2] - th[f][2], acc[3] - th[f][3]));
        if (dmax >= 0.f) {  // rare: ~1.3 candidates per token over all 16 splits
#pragma unroll
          for (int r = 0; r < 4; ++r) {
            if (acc[r] >= th[f][r]) {
              int tok = tokBase + f * 16 + quad * 4 + r;
              int pos = atomicAdd(&g_candcnt[tok], 1);
              if (pos < CAP) g_cand[tok * CAP + pos] = code;
            }
          }
        }
      }
    }
    __syncthreads();
    p ^= 1;
  }
}

// k_final: per block (64 tokens): resolve flagged tokens with EXACT fp64 scoring
// (qc recomputed from cb/W/b in fp64 -> score (z.qc)/||qc||, monotone to ref's zn.cn),
// then gather + straight-through + loss. Block-local: no cross-block idx dependency.
__global__ __launch_bounds__(256) void k_final(const float* __restrict__ z,
                                               const float* __restrict__ cb,
                                               const float* __restrict__ pw,
                                               const float* __restrict__ pb,
                                               float* __restrict__ out0,
                                               float* __restrict__ out1,
                                               float* __restrict__ out2) {
  __shared__ double Wl[64 * 65];  // fp64 W, padded (2-way bank alias only)
  __shared__ int wl[64];
  __shared__ int idxs[64];
  __shared__ int nfl;
  int tid = threadIdx.x;
  int wave = tid >> 6, lane = tid & 63;
  int base = blockIdx.x * 64;

  for (int e = tid; e < 4096; e += 256) {
    int j = e >> 6, k = e & 63;
    Wl[j * 65 + k] = (double)pw[(size_t)j * 64 + k];
  }
  if (tid == 0) nfl = 0;
  __syncthreads();
  if (tid < 64) {
    int tok = base + tid;
    int cnt = g_candcnt[tok];
    if (cnt <= 1) idxs[tid] = g_cand[tok * CAP];  // cnt >= 1 guaranteed (top re-found)
    else { int p = atomicAdd(&nfl, 1); wl[p] = tid; }
  }
  __syncthreads();
  int n = nfl;
  for (int e = wave; e < n; e += 4) {
    int tl = wl[e];
    int tok = base + tl;
    int cnt = g_candcnt[tok];
    double zj = (double)z[(size_t)tok * 64 + lane];
    double bj = (double)pb[lane];
    double best = -1.0e300;
    int bi = 0x7FFFFFFF;
    int lim = (cnt <= CAP) ? cnt : 0;  // overflow -> full scan below
    for (int c = 0; c < lim; ++c) {
      int code = g_cand[tok * CAP + c];
      float cbv = cb[(size_t)code * 64 + lane];
      double acc = bj;
#pragma unroll
      for (int k = 0; k < 64; ++k)
        acc = fma((double)__shfl(cbv, k, 64), Wl[lane * 65 + k], acc);
      double s = wave_sum64d(zj * acc);
      double n2 = wave_sum64d(acc * acc);
      double key = s / fmax(sqrt(n2), 1e-12);
      if (key > best || (key == best && code < bi)) { best = key; bi = code; }
    }
    if (cnt > CAP) {  // correctness fallback; never fires on this margin (observed max <= 8)
      for (int code = 0; code < NCODES; ++code) {
        float cbv = cb[(size_t)code * 64 + lane];
        double acc = bj;
#pragma unroll
        for (int k = 0; k < 64; ++k)
          acc = fma((double)__shfl(cbv, k, 64), Wl[lane * 65 + k], acc);
        double s = wave_sum64d(zj * acc);
        double n2 = wave_sum64d(acc * acc);
        double key = s / fmax(sqrt(n2), 1e-12);
        if (key > best || (key == best && code < bi)) { best = key; bi = code; }
      }
    }
    if (lane == 0) idxs[tl] = bi;
  }
  __syncthreads();

  int w = wave, j = lane;
  float lsum = 0.f;
  for (int r = 0; r < 16; ++r) {
    int tl = w * 16 + r;
    int tok = base + tl;
    int idx = idxs[tl];
    float q = g_qcb[(size_t)idx * 64 + j];
    float zv = z[(size_t)tok * 64 + j];
    float d = q - zv;
    out0[(size_t)tok * 64 + j] = zv + d;  // z + (q - z), ref op order
    lsum = fmaf(d, d, lsum);
    if (j == 0) out2[tok] = (float)idx;
  }
  float tot = wave_sum64(lsum);
  if (j == 0) atomicAdd(&g_loss, tot);
  __syncthreads();
  if (tid == 0) {
    __threadfence();
    int d = atomicAdd(&g_done, 1);
    if (d == (int)gridDim.x - 1) {
      __threadfence();
      float lv = atomicAdd(&g_loss, 0.0f);
      out1[0] = 1.25f * lv / 1048576.0f;  // commitment == codebook numerically
    }
  }
}

extern "C" void kernel_launch(void* const* d_in, const int* in_sizes, int n_in,
                              void* d_out, int out_size, void* d_ws, size_t ws_size,
                              hipStream_t stream) {
  const float* z = (const float*)d_in[0];
  const float* cb = (const float*)d_in[1];
  const float* pw = (const float*)d_in[2];
  const float* pb = (const float*)d_in[3];
  // d_in[4] (scale) unused: argmin invariant to positive scale

  float* out0 = (float*)d_out;
  float* out1 = out0 + (size_t)NTOK * DIM;
  float* out2 = out1 + 1;

  hipLaunchKernelGGL(k_prep, dim3(512), dim3(256), 0, stream, cb, pw, pb, z);
  hipLaunchKernelGGL(k_mfma1, dim3(2048), dim3(256), 0, stream);
  hipLaunchKernelGGL(k_mfma2, dim3(2048), dim3(256), 0, stream);
  hipLaunchKernelGGL(k_final, dim3(256), dim3(256), 0, stream, z, cb, pw, pb, out0, out1, out2);
}

// Round 11
// 232.036 us; speedup vs baseline: 1.0429x; 1.0429x over previous
//
#include <hip/hip_runtime.h>
#include <hip/hip_bf16.h>

// SimVQ: z[16,1024,64] f32, codebook[16384,64] f32, proj_w[64,64] f32, proj_b[64] f32, scale f32
// Outputs (fp32, concat): quantized_st[1048576], vq_loss[1], idx[16384]
// r11 == r10 resubmitted verbatim (r10 bench was an infra failure: "container failed twice";
// kernel never executed). r10: GEMM passes at r8's measured-best config (8 splits, 128-code
// dbuf stages, 1024 blocks). k_prep keeps r9's Ozaki-MFMA projection. k_final: wave-per-token
// arbiter with lane-parallel fp64 qc recomputation, fused gather/out/loss. 4 launches.
// Margin scheme proven r5-r9: pass1 mfma top value, pass2 collect within 8e-3
// (bf16 quant err <= 4e-3 + proj err ~1e-5), fp64 arbiter.

#define NCODES 16384
#define NTOK   16384
#define DIM    64
#define MARGIN_MFMA 8e-3f
#define CAP    16

typedef __attribute__((ext_vector_type(8))) short bf16x8;
typedef __attribute__((ext_vector_type(4))) float f32x4;
#define GLOBAL_AS __attribute__((address_space(1)))
#define LDS_AS    __attribute__((address_space(3)))

__device__ float  g_qcb[NCODES * DIM];   // 4 MB projected codebook fp32 (gather source)
__device__ short  g_cnb[NCODES * DIM];   // 2 MB l2norm(qcb) bf16 row-major (MFMA B)
__device__ short  g_znb[NTOK * DIM];     // 2 MB l2norm(z)  bf16 row-major (MFMA A)
__device__ unsigned g_topu[NTOK];        // orderable-encoded mfma top-1 value
__device__ int    g_candcnt[NTOK];
__device__ int    g_cand[NTOK * CAP];    // 1 MB
__device__ float  g_loss;
__device__ int    g_done;

__device__ __forceinline__ float wave_sum64(float v) {
#pragma unroll
  for (int o = 32; o > 0; o >>= 1) v += __shfl_xor(v, o, 64);
  return v;
}
__device__ __forceinline__ short f2bf(float f) {
  __hip_bfloat16 h = __float2bfloat16(f);
  return *reinterpret_cast<short*>(&h);
}
__device__ __forceinline__ float bf2f(short s) {
  __hip_bfloat16 h = *reinterpret_cast<__hip_bfloat16*>(&s);
  return __bfloat162float(h);
}
__device__ __forceinline__ void split8(const float* v, bf16x8& hi, bf16x8& lo) {
#pragma unroll
  for (int i = 0; i < 8; ++i) {
    float f = v[i];
    short h = f2bf(f);
    hi[i] = h;
    lo[i] = f2bf(f - bf2f(h));
  }
}

// k_prep: blocks [0,256): projection qc = cb@W^T + b via Ozaki hi/lo bf16 MFMA (fp32-class
// accuracy) -> fp32 qcb, bf16 cnb. blocks [256,512): znorm -> bf16 znb + zero per-call state.
// MFMA layouts (HW-proven): A m=col,k=quad*8+i ; B n=col,k=quad*8+i ; C/D m=quad*4+r,n=col.
__global__ __launch_bounds__(256) void k_prep(const float* __restrict__ cb,
                                              const float* __restrict__ pw,
                                              const float* __restrict__ pb,
                                              const float* __restrict__ z) {
  int tid = threadIdx.x;
  int wave = tid >> 6, lane = tid & 63, quad = lane >> 4, col = lane & 15;
  if (blockIdx.x < 256) {
    int rowBase = blockIdx.x * 64 + wave * 16;
    const float* cr = cb + (size_t)(rowBase + col) * 64 + quad * 8;
    bf16x8 ah0, al0, ah1, al1;
    split8(cr, ah0, al0);
    split8(cr + 32, ah1, al1);
    float vals[4][4];
    float nr[4] = {0.f, 0.f, 0.f, 0.f};
    const f32x4 fz = {0.f, 0.f, 0.f, 0.f};
#pragma unroll
    for (int nt = 0; nt < 4; ++nt) {
      int j = col + 16 * nt;
      const float* wr = pw + (size_t)j * 64 + quad * 8;
      bf16x8 bh0, bl0, bh1, bl1;
      split8(wr, bh0, bl0);
      split8(wr + 32, bh1, bl1);
      f32x4 d = __builtin_amdgcn_mfma_f32_16x16x32_bf16(ah0, bh0, fz, 0, 0, 0);
      d = __builtin_amdgcn_mfma_f32_16x16x32_bf16(ah1, bh1, d, 0, 0, 0);
      d = __builtin_amdgcn_mfma_f32_16x16x32_bf16(ah0, bl0, d, 0, 0, 0);
      d = __builtin_amdgcn_mfma_f32_16x16x32_bf16(ah1, bl1, d, 0, 0, 0);
      d = __builtin_amdgcn_mfma_f32_16x16x32_bf16(al0, bh0, d, 0, 0, 0);
      d = __builtin_amdgcn_mfma_f32_16x16x32_bf16(al1, bh1, d, 0, 0, 0);
      float bj = pb[j];
#pragma unroll
      for (int r = 0; r < 4; ++r) {
        float v = d[r] + bj;
        vals[nt][r] = v;
        nr[r] = fmaf(v, v, nr[r]);
      }
    }
#pragma unroll
    for (int r = 0; r < 4; ++r) {
      float v = nr[r];
      v += __shfl_xor(v, 1, 64);
      v += __shfl_xor(v, 2, 64);
      v += __shfl_xor(v, 4, 64);
      v += __shfl_xor(v, 8, 64);
      nr[r] = 1.0f / fmaxf(sqrtf(v), 1e-12f);
    }
#pragma unroll
    for (int nt = 0; nt < 4; ++nt)
#pragma unroll
      for (int r = 0; r < 4; ++r) {
        int row = rowBase + quad * 4 + r;
        int j = col + 16 * nt;
        g_qcb[(size_t)row * 64 + j] = vals[nt][r];
        g_cnb[(size_t)row * 64 + j] = f2bf(vals[nt][r] * nr[r]);
      }
  } else {
    int zb = blockIdx.x - 256;
    int gid = zb * 256 + tid;
    if (gid < NTOK) { g_topu[gid] = 0u; g_candcnt[gid] = 0; }
    if (gid == 0) { g_loss = 0.f; g_done = 0; }
    int base = zb * 64;
    for (int r = 0; r < 16; ++r) {
      int row = base + wave * 16 + r;
      float v = z[(size_t)row * 64 + lane];
      float tot = wave_sum64(v * v);
      g_znb[(size_t)row * 64 + lane] = f2bf(v / fmaxf(sqrtf(tot), 1e-12f));
    }
  }
}

// GEMM core (r8's measured-best): grid = 128 tokBlocks x 8 splits = 1024 blocks (4/CU),
// 4 waves/block, wave owns 32 tokens. B double-buffered 128-code (16KB) stages via
// global_load_lds width-16, XOR-swizzled; ONE barrier/stage.
__global__ __launch_bounds__(256) void k_mfma1() {
  __shared__ __align__(16) short smB[2][8192];
  int tid = threadIdx.x;
  int wave = tid >> 6, lane = tid & 63;
  int quad = lane >> 4, col = lane & 15;
  int tokBlock = blockIdx.x >> 3, split = blockIdx.x & 7;
  int tokBase = tokBlock * 128 + wave * 32;

  const short* za = g_znb + (size_t)(tokBase + col) * 64 + quad * 8;
  bf16x8 A0[2], A1[2];
#pragma unroll
  for (int f = 0; f < 2; ++f) {
    A0[f] = *(const bf16x8*)(za + f * 16 * 64);
    A1[f] = *(const bf16x8*)(za + f * 16 * 64 + 32);
  }
  float m[2][4];
#pragma unroll
  for (int f = 0; f < 2; ++f)
#pragma unroll
    for (int r = 0; r < 4; ++r) m[f][r] = -3.0e38f;

  const char* gsplit = (const char*)(g_cnb + (size_t)split * 2048 * 64);
  int x = col & 7;
  int s0off = ((quad ^ x) << 3);
  int s1off = (((4 | quad) ^ x) << 3);
  int goff[4];
#pragma unroll
  for (int i = 0; i < 4; ++i) {
    int cidx = wave * 256 + i * 64 + lane;
    int row = cidx >> 3, sw = cidx & 7;
    goff[i] = row * 128 + ((sw ^ (row & 7)) << 4);
  }

#pragma unroll
  for (int i = 0; i < 4; ++i)
    __builtin_amdgcn_global_load_lds((const GLOBAL_AS void*)(gsplit + goff[i]),
                                     (LDS_AS void*)(&smB[0][wave * 2048 + i * 512]), 16, 0, 0);
  __syncthreads();

  int p = 0;
  for (int s = 0; s < 16; ++s) {
    if (s < 15) {
      const char* gb = gsplit + (size_t)(s + 1) * 16384;
#pragma unroll
      for (int i = 0; i < 4; ++i)
        __builtin_amdgcn_global_load_lds((const GLOBAL_AS void*)(gb + goff[i]),
                                         (LDS_AS void*)(&smB[p ^ 1][wave * 2048 + i * 512]),
                                         16, 0, 0);
    }
    const short* bufp = smB[p];
#pragma unroll
    for (int t = 0; t < 8; ++t) {
      const short* lb = bufp + (t * 16 + col) * 64;
      bf16x8 b0 = *(const bf16x8*)(lb + s0off);
      bf16x8 b1 = *(const bf16x8*)(lb + s1off);
#pragma unroll
      for (int f = 0; f < 2; ++f) {
        f32x4 acc = {0.f, 0.f, 0.f, 0.f};
        acc = __builtin_amdgcn_mfma_f32_16x16x32_bf16(A0[f], b0, acc, 0, 0, 0);
        acc = __builtin_amdgcn_mfma_f32_16x16x32_bf16(A1[f], b1, acc, 0, 0, 0);
#pragma unroll
        for (int r = 0; r < 4; ++r) m[f][r] = fmaxf(m[f][r], acc[r]);
      }
    }
    __syncthreads();
    p ^= 1;
  }

#pragma unroll
  for (int f = 0; f < 2; ++f)
#pragma unroll
    for (int r = 0; r < 4; ++r) {
      float v = m[f][r];
      v = fmaxf(v, __shfl_xor(v, 1, 64));
      v = fmaxf(v, __shfl_xor(v, 2, 64));
      v = fmaxf(v, __shfl_xor(v, 4, 64));
      v = fmaxf(v, __shfl_xor(v, 8, 64));
      if (col == 0) {
        unsigned b = __float_as_uint(v);
        unsigned e = (b & 0x80000000u) ? ~b : (b | 0x80000000u);
        atomicMax(&g_topu[tokBase + f * 16 + quad * 4 + r], e);
      }
    }
}

__global__ __launch_bounds__(256) void k_mfma2() {
  __shared__ __align__(16) short smB[2][8192];
  int tid = threadIdx.x;
  int wave = tid >> 6, lane = tid & 63;
  int quad = lane >> 4, col = lane & 15;
  int tokBlock = blockIdx.x >> 3, split = blockIdx.x & 7;
  int tokBase = tokBlock * 128 + wave * 32;

  const short* za = g_znb + (size_t)(tokBase + col) * 64 + quad * 8;
  bf16x8 A0[2], A1[2];
#pragma unroll
  for (int f = 0; f < 2; ++f) {
    A0[f] = *(const bf16x8*)(za + f * 16 * 64);
    A1[f] = *(const bf16x8*)(za + f * 16 * 64 + 32);
  }
  float th[2][4];
#pragma unroll
  for (int f = 0; f < 2; ++f)
#pragma unroll
    for (int r = 0; r < 4; ++r) {
      unsigned u = g_topu[tokBase + f * 16 + quad * 4 + r];
      unsigned b = (u & 0x80000000u) ? (u & 0x7FFFFFFFu) : ~u;
      th[f][r] = __uint_as_float(b) - MARGIN_MFMA;
    }

  const char* gsplit = (const char*)(g_cnb + (size_t)split * 2048 * 64);
  int x = col & 7;
  int s0off = ((quad ^ x) << 3);
  int s1off = (((4 | quad) ^ x) << 3);
  int goff[4];
#pragma unroll
  for (int i = 0; i < 4; ++i) {
    int cidx = wave * 256 + i * 64 + lane;
    int row = cidx >> 3, sw = cidx & 7;
    goff[i] = row * 128 + ((sw ^ (row & 7)) << 4);
  }

#pragma unroll
  for (int i = 0; i < 4; ++i)
    __builtin_amdgcn_global_load_lds((const GLOBAL_AS void*)(gsplit + goff[i]),
                                     (LDS_AS void*)(&smB[0][wave * 2048 + i * 512]), 16, 0, 0);
  __syncthreads();

  int codeB = split * 2048 + col;
  int p = 0;
  for (int s = 0; s < 16; ++s) {
    if (s < 15) {
      const char* gb = gsplit + (size_t)(s + 1) * 16384;
#pragma unroll
      for (int i = 0; i < 4; ++i)
        __builtin_amdgcn_global_load_lds((const GLOBAL_AS void*)(gb + goff[i]),
                                         (LDS_AS void*)(&smB[p ^ 1][wave * 2048 + i * 512]),
                                         16, 0, 0);
    }
    const short* bufp = smB[p];
#pragma unroll
    for (int t = 0; t < 8; ++t) {
      const short* lb = bufp + (t * 16 + col) * 64;
      bf16x8 b0 = *(const bf16x8*)(lb + s0off);
      bf16x8 b1 = *(const bf16x8*)(lb + s1off);
      int code = codeB + s * 128 + t * 16;
#pragma unroll
      for (int f = 0; f < 2; ++f) {
        f32x4 acc = {0.f, 0.f, 0.f, 0.f};
        acc = __builtin_amdgcn_mfma_f32_16x16x32_bf16(A0[f], b0, acc, 0, 0, 0);
        acc = __builtin_amdgcn_mfma_f32_16x16x32_bf16(A1[f], b1, acc, 0, 0, 0);
        float dmax = fmaxf(fmaxf(acc[0] - th[f][0], acc[1] - th[f][1]),
                           fmaxf(acc[2] - th[f][2], acc[3] - th[f][3]));
        if (dmax >= 0.f) {  // rare: ~1.3 appends per token total
#pragma unroll
          for (int r = 0; r < 4; ++r) {
            if (acc[r] >= th[f][r]) {
              int tok = tokBase + f * 16 + quad * 4 + r;
              int pos = atomicAdd(&g_candcnt[tok], 1);
              if (pos < CAP) g_cand[tok * CAP + pos] = code;
            }
          }
        }
      }
    }
    __syncthreads();
    p ^= 1;
  }
}

// k_final: wave-per-token arbiter + gather/out/loss. Grid 1024x256 -> 4096 waves x 4 tokens.
// Flagged tokens (cnt>=2): per candidate, stage cb row to LDS (coalesced), then LANE-PARALLEL
// fp64 recompute qc_j = b_j + sum_k W[j,k] cb_k (acc chain only, no cross-lane serialization),
// score (z.qc)/||qc|| (monotone to ref's zn.cn), tie -> smallest code. NO __syncthreads in
// divergent paths (wave-coherent LDS; compiler inserts lgkmcnt).
__global__ __launch_bounds__(256) void k_final(const float* __restrict__ z,
                                               const float* __restrict__ cb,
                                               const float* __restrict__ pw,
                                               const float* __restrict__ pb,
                                               float* __restrict__ out0,
                                               float* __restrict__ out1,
                                               float* __restrict__ out2) {
  __shared__ double Wl[64 * 65];    // Wl[j*65+k] = W[j][k] fp64
  __shared__ float cbl[4][64];      // per-wave staged cb row
  int tid = threadIdx.x;
  int wave = tid >> 6, lane = tid & 63;

  for (int e = tid; e < 4096; e += 256) {
    int j = e >> 6, k = e & 63;
    Wl[j * 65 + k] = (double)pw[(size_t)j * 64 + k];
  }
  __syncthreads();  // uniform: before any divergence

  double bj = (double)pb[lane];
  int wg = blockIdx.x * 4 + wave;
  float lsum = 0.f;

  for (int i = 0; i < 4; ++i) {
    int tok = wg * 4 + i;
    int cnt = g_candcnt[tok];  // same addr all lanes -> broadcast
    int idx;
    if (cnt <= 1) {
      idx = g_cand[tok * CAP];  // cnt >= 1 guaranteed (global top always appends)
    } else {
      double zj = (double)z[(size_t)tok * 64 + lane];
      double best = -1.0e300;
      int bi = 0x7FFFFFFF;
      int lim = (cnt <= CAP) ? cnt : 0;  // overflow -> full scan (never fires; max seen 8)
      for (int c = 0; c < lim; ++c) {
        int code = g_cand[tok * CAP + c];
        cbl[wave][lane] = cb[(size_t)code * 64 + lane];
        double qc = bj;
#pragma unroll 16
        for (int k = 0; k < 64; ++k)
          qc = fma(Wl[lane * 65 + k], (double)cbl[wave][k], qc);
        double s = zj * qc, n2 = qc * qc;
#pragma unroll
        for (int o = 32; o > 0; o >>= 1) {
          s += __shfl_xor(s, o, 64);
          n2 += __shfl_xor(n2, o, 64);
        }
        double key = s / fmax(sqrt(n2), 1e-12);
        if (key > best || (key == best && code < bi)) { best = key; bi = code; }
      }
      if (cnt > CAP) {
        for (int code = 0; code < NCODES; ++code) {
          cbl[wave][lane] = cb[(size_t)code * 64 + lane];
          double qc = bj;
#pragma unroll 16
          for (int k = 0; k < 64; ++k)
            qc = fma(Wl[lane * 65 + k], (double)cbl[wave][k], qc);
          double s = zj * qc, n2 = qc * qc;
#pragma unroll
          for (int o = 32; o > 0; o >>= 1) {
            s += __shfl_xor(s, o, 64);
            n2 += __shfl_xor(n2, o, 64);
          }
          double key = s / fmax(sqrt(n2), 1e-12);
          if (key > best || (key == best && code < bi)) { best = key; bi = code; }
        }
      }
      idx = bi;
    }
    // gather + straight-through + loss partial (idx wave-uniform -> coalesced)
    float q = g_qcb[(size_t)idx * 64 + lane];
    float zv = z[(size_t)tok * 64 + lane];
    float d = q - zv;
    out0[(size_t)tok * 64 + lane] = zv + d;  // z + (q - z), ref op order
    lsum = fmaf(d, d, lsum);
    if (lane == 0) out2[tok] = (float)idx;
  }
  float tot = wave_sum64(lsum);
  if (lane == 0) atomicAdd(&g_loss, tot);
  __syncthreads();
  if (tid == 0) {
    __threadfence();
    int d = atomicAdd(&g_done, 1);
    if (d == (int)gridDim.x - 1) {
      __threadfence();
      float lv = atomicAdd(&g_loss, 0.0f);
      out1[0] = 1.25f * lv / 1048576.0f;  // commitment == codebook numerically
    }
  }
}

extern "C" void kernel_launch(void* const* d_in, const int* in_sizes, int n_in,
                              void* d_out, int out_size, void* d_ws, size_t ws_size,
                              hipStream_t stream) {
  const float* z = (const float*)d_in[0];
  const float* cb = (const float*)d_in[1];
  const float* pw = (const float*)d_in[2];
  const float* pb = (const float*)d_in[3];
  // d_in[4] (scale) unused: argmin invariant to positive scale

  float* out0 = (float*)d_out;
  float* out1 = out0 + (size_t)NTOK * DIM;
  float* out2 = out1 + 1;

  hipLaunchKernelGGL(k_prep, dim3(512), dim3(256), 0, stream, cb, pw, pb, z);
  hipLaunchKernelGGL(k_mfma1, dim3(1024), dim3(256), 0, stream);
  hipLaunchKernelGGL(k_mfma2, dim3(1024), dim3(256), 0, stream);
  hipLaunchKernelGGL(k_final, dim3(1024), dim3(256), 0, stream, z, cb, pw, pb, out0, out1, out2);
}

// Round 14
// 203.349 us; speedup vs baseline: 1.1900x; 1.1411x over previous
//
#include <hip/hip_runtime.h>
#include <hip/hip_bf16.h>

// SimVQ: z[16,1024,64] f32, codebook[16384,64] f32, proj_w[64,64] f32, proj_b[64] f32, scale f32
// Outputs (fp32, concat): quantized_st[1048576], vq_loss[1], idx[16384]
// r14 = r12 architecture, de-risked after 4/4 infra failures on the r12/r13 source:
// __ballot/__popcll removed (k_scan now LDS flags + thread-0 serial scan; only r11-proven
// intrinsics remain), CAP 32->16. Design: GEMM passes identical to r11 (measured-good);
// r11's 87µs k_final (latency-bound: worst-wave serial fp64 chains + same-address atomics)
// split into k_scan (worklist of cnt>=2 tokens, 1 atomic/block), k_arb (1024 waves stride
// the worklist, lane-parallel fp64 scoring), k_out (gather/outputs, plain-stored loss
// partials), k_loss (deterministic sum). Margin scheme proven r5-r11: pass1 mfma top value,
// pass2 collect within 8e-3 (bf16 quant err <= 4e-3 + Ozaki proj err ~1e-5), fp64 arbiter.

#define NCODES 16384
#define NTOK   16384
#define DIM    64
#define MARGIN_MFMA 8e-3f
#define CAP    16

typedef __attribute__((ext_vector_type(8))) short bf16x8;
typedef __attribute__((ext_vector_type(4))) float f32x4;
#define GLOBAL_AS __attribute__((address_space(1)))
#define LDS_AS    __attribute__((address_space(3)))

__device__ float  g_qcb[NCODES * DIM];   // 4 MB projected codebook fp32 (gather source)
__device__ short  g_cnb[NCODES * DIM];   // 2 MB l2norm(qcb) bf16 row-major (MFMA B)
__device__ short  g_znb[NTOK * DIM];     // 2 MB l2norm(z)  bf16 row-major (MFMA A)
__device__ unsigned g_topu[NTOK];        // orderable-encoded mfma top-1 value
__device__ int    g_candcnt[NTOK];
__device__ int    g_cand[NTOK * CAP];    // 1 MB; slot 0 holds the winner after k_arb
__device__ int    g_wl[NTOK];            // flagged-token worklist
__device__ int    g_wln;
__device__ float  g_partial[512];        // per-block loss partials (all written every call)

__device__ __forceinline__ float wave_sum64(float v) {
#pragma unroll
  for (int o = 32; o > 0; o >>= 1) v += __shfl_xor(v, o, 64);
  return v;
}
__device__ __forceinline__ short f2bf(float f) {
  __hip_bfloat16 h = __float2bfloat16(f);
  return *reinterpret_cast<short*>(&h);
}
__device__ __forceinline__ float bf2f(short s) {
  __hip_bfloat16 h = *reinterpret_cast<__hip_bfloat16*>(&s);
  return __bfloat162float(h);
}
__device__ __forceinline__ void split8(const float* v, bf16x8& hi, bf16x8& lo) {
#pragma unroll
  for (int i = 0; i < 8; ++i) {
    float f = v[i];
    short h = f2bf(f);
    hi[i] = h;
    lo[i] = f2bf(f - bf2f(h));
  }
}

// k_prep: blocks [0,256): projection qc = cb@W^T + b via Ozaki hi/lo bf16 MFMA (fp32-class
// accuracy) -> fp32 qcb, bf16 cnb. blocks [256,512): znorm -> bf16 znb + zero per-call state.
__global__ __launch_bounds__(256) void k_prep(const float* __restrict__ cb,
                                              const float* __restrict__ pw,
                                              const float* __restrict__ pb,
                                              const float* __restrict__ z) {
  int tid = threadIdx.x;
  int wave = tid >> 6, lane = tid & 63, quad = lane >> 4, col = lane & 15;
  if (blockIdx.x < 256) {
    int rowBase = blockIdx.x * 64 + wave * 16;
    const float* cr = cb + (size_t)(rowBase + col) * 64 + quad * 8;
    bf16x8 ah0, al0, ah1, al1;
    split8(cr, ah0, al0);
    split8(cr + 32, ah1, al1);
    float vals[4][4];
    float nr[4] = {0.f, 0.f, 0.f, 0.f};
    const f32x4 fz = {0.f, 0.f, 0.f, 0.f};
#pragma unroll
    for (int nt = 0; nt < 4; ++nt) {
      int j = col + 16 * nt;
      const float* wr = pw + (size_t)j * 64 + quad * 8;
      bf16x8 bh0, bl0, bh1, bl1;
      split8(wr, bh0, bl0);
      split8(wr + 32, bh1, bl1);
      f32x4 d = __builtin_amdgcn_mfma_f32_16x16x32_bf16(ah0, bh0, fz, 0, 0, 0);
      d = __builtin_amdgcn_mfma_f32_16x16x32_bf16(ah1, bh1, d, 0, 0, 0);
      d = __builtin_amdgcn_mfma_f32_16x16x32_bf16(ah0, bl0, d, 0, 0, 0);
      d = __builtin_amdgcn_mfma_f32_16x16x32_bf16(ah1, bl1, d, 0, 0, 0);
      d = __builtin_amdgcn_mfma_f32_16x16x32_bf16(al0, bh0, d, 0, 0, 0);
      d = __builtin_amdgcn_mfma_f32_16x16x32_bf16(al1, bh1, d, 0, 0, 0);
      float bj = pb[j];
#pragma unroll
      for (int r = 0; r < 4; ++r) {
        float v = d[r] + bj;
        vals[nt][r] = v;
        nr[r] = fmaf(v, v, nr[r]);
      }
    }
#pragma unroll
    for (int r = 0; r < 4; ++r) {
      float v = nr[r];
      v += __shfl_xor(v, 1, 64);
      v += __shfl_xor(v, 2, 64);
      v += __shfl_xor(v, 4, 64);
      v += __shfl_xor(v, 8, 64);
      nr[r] = 1.0f / fmaxf(sqrtf(v), 1e-12f);
    }
#pragma unroll
    for (int nt = 0; nt < 4; ++nt)
#pragma unroll
      for (int r = 0; r < 4; ++r) {
        int row = rowBase + quad * 4 + r;
        int j = col + 16 * nt;
        g_qcb[(size_t)row * 64 + j] = vals[nt][r];
        g_cnb[(size_t)row * 64 + j] = f2bf(vals[nt][r] * nr[r]);
      }
  } else {
    int zb = blockIdx.x - 256;
    int gid = zb * 256 + tid;
    if (gid < NTOK) { g_topu[gid] = 0u; g_candcnt[gid] = 0; }
    if (gid == 0) g_wln = 0;
    int base = zb * 64;
    for (int r = 0; r < 16; ++r) {
      int row = base + wave * 16 + r;
      float v = z[(size_t)row * 64 + lane];
      float tot = wave_sum64(v * v);
      g_znb[(size_t)row * 64 + lane] = f2bf(v / fmaxf(sqrtf(tot), 1e-12f));
    }
  }
}

// GEMM core (r8/r11 measured-best): grid = 128 tokBlocks x 8 splits = 1024 blocks (4/CU),
// 4 waves/block, wave owns 32 tokens. B double-buffered 128-code (16KB) stages via
// global_load_lds width-16, XOR-swizzled; ONE barrier/stage.
__global__ __launch_bounds__(256) void k_mfma1() {
  __shared__ __align__(16) short smB[2][8192];
  int tid = threadIdx.x;
  int wave = tid >> 6, lane = tid & 63;
  int quad = lane >> 4, col = lane & 15;
  int tokBlock = blockIdx.x >> 3, split = blockIdx.x & 7;
  int tokBase = tokBlock * 128 + wave * 32;

  const short* za = g_znb + (size_t)(tokBase + col) * 64 + quad * 8;
  bf16x8 A0[2], A1[2];
#pragma unroll
  for (int f = 0; f < 2; ++f) {
    A0[f] = *(const bf16x8*)(za + f * 16 * 64);
    A1[f] = *(const bf16x8*)(za + f * 16 * 64 + 32);
  }
  float m[2][4];
#pragma unroll
  for (int f = 0; f < 2; ++f)
#pragma unroll
    for (int r = 0; r < 4; ++r) m[f][r] = -3.0e38f;

  const char* gsplit = (const char*)(g_cnb + (size_t)split * 2048 * 64);
  int x = col & 7;
  int s0off = ((quad ^ x) << 3);
  int s1off = (((4 | quad) ^ x) << 3);
  int goff[4];
#pragma unroll
  for (int i = 0; i < 4; ++i) {
    int cidx = wave * 256 + i * 64 + lane;
    int row = cidx >> 3, sw = cidx & 7;
    goff[i] = row * 128 + ((sw ^ (row & 7)) << 4);
  }

#pragma unroll
  for (int i = 0; i < 4; ++i)
    __builtin_amdgcn_global_load_lds((const GLOBAL_AS void*)(gsplit + goff[i]),
                                     (LDS_AS void*)(&smB[0][wave * 2048 + i * 512]), 16, 0, 0);
  __syncthreads();

  int p = 0;
  for (int s = 0; s < 16; ++s) {
    if (s < 15) {
      const char* gb = gsplit + (size_t)(s + 1) * 16384;
#pragma unroll
      for (int i = 0; i < 4; ++i)
        __builtin_amdgcn_global_load_lds((const GLOBAL_AS void*)(gb + goff[i]),
                                         (LDS_AS void*)(&smB[p ^ 1][wave * 2048 + i * 512]),
                                         16, 0, 0);
    }
    const short* bufp = smB[p];
#pragma unroll
    for (int t = 0; t < 8; ++t) {
      const short* lb = bufp + (t * 16 + col) * 64;
      bf16x8 b0 = *(const bf16x8*)(lb + s0off);
      bf16x8 b1 = *(const bf16x8*)(lb + s1off);
#pragma unroll
      for (int f = 0; f < 2; ++f) {
        f32x4 acc = {0.f, 0.f, 0.f, 0.f};
        acc = __builtin_amdgcn_mfma_f32_16x16x32_bf16(A0[f], b0, acc, 0, 0, 0);
        acc = __builtin_amdgcn_mfma_f32_16x16x32_bf16(A1[f], b1, acc, 0, 0, 0);
#pragma unroll
        for (int r = 0; r < 4; ++r) m[f][r] = fmaxf(m[f][r], acc[r]);
      }
    }
    __syncthreads();
    p ^= 1;
  }

#pragma unroll
  for (int f = 0; f < 2; ++f)
#pragma unroll
    for (int r = 0; r < 4; ++r) {
      float v = m[f][r];
      v = fmaxf(v, __shfl_xor(v, 1, 64));
      v = fmaxf(v, __shfl_xor(v, 2, 64));
      v = fmaxf(v, __shfl_xor(v, 4, 64));
      v = fmaxf(v, __shfl_xor(v, 8, 64));
      if (col == 0) {
        unsigned b = __float_as_uint(v);
        unsigned e = (b & 0x80000000u) ? ~b : (b | 0x80000000u);
        atomicMax(&g_topu[tokBase + f * 16 + quad * 4 + r], e);
      }
    }
}

__global__ __launch_bounds__(256) void k_mfma2() {
  __shared__ __align__(16) short smB[2][8192];
  int tid = threadIdx.x;
  int wave = tid >> 6, lane = tid & 63;
  int quad = lane >> 4, col = lane & 15;
  int tokBlock = blockIdx.x >> 3, split = blockIdx.x & 7;
  int tokBase = tokBlock * 128 + wave * 32;

  const short* za = g_znb + (size_t)(tokBase + col) * 64 + quad * 8;
  bf16x8 A0[2], A1[2];
#pragma unroll
  for (int f = 0; f < 2; ++f) {
    A0[f] = *(const bf16x8*)(za + f * 16 * 64);
    A1[f] = *(const bf16x8*)(za + f * 16 * 64 + 32);
  }
  float th[2][4];
#pragma unroll
  for (int f = 0; f < 2; ++f)
#pragma unroll
    for (int r = 0; r < 4; ++r) {
      unsigned u = g_topu[tokBase + f * 16 + quad * 4 + r];
      unsigned b = (u & 0x80000000u) ? (u & 0x7FFFFFFFu) : ~u;
      th[f][r] = __uint_as_float(b) - MARGIN_MFMA;
    }

  const char* gsplit = (const char*)(g_cnb + (size_t)split * 2048 * 64);
  int x = col & 7;
  int s0off = ((quad ^ x) << 3);
  int s1off = (((4 | quad) ^ x) << 3);
  int goff[4];
#pragma unroll
  for (int i = 0; i < 4; ++i) {
    int cidx = wave * 256 + i * 64 + lane;
    int row = cidx >> 3, sw = cidx & 7;
    goff[i] = row * 128 + ((sw ^ (row & 7)) << 4);
  }

#pragma unroll
  for (int i = 0; i < 4; ++i)
    __builtin_amdgcn_global_load_lds((const GLOBAL_AS void*)(gsplit + goff[i]),
                                     (LDS_AS void*)(&smB[0][wave * 2048 + i * 512]), 16, 0, 0);
  __syncthreads();

  int codeB = split * 2048 + col;
  int p = 0;
  for (int s = 0; s < 16; ++s) {
    if (s < 15) {
      const char* gb = gsplit + (size_t)(s + 1) * 16384;
#pragma unroll
      for (int i = 0; i < 4; ++i)
        __builtin_amdgcn_global_load_lds((const GLOBAL_AS void*)(gb + goff[i]),
                                         (LDS_AS void*)(&smB[p ^ 1][wave * 2048 + i * 512]),
                                         16, 0, 0);
    }
    const short* bufp = smB[p];
#pragma unroll
    for (int t = 0; t < 8; ++t) {
      const short* lb = bufp + (t * 16 + col) * 64;
      bf16x8 b0 = *(const bf16x8*)(lb + s0off);
      bf16x8 b1 = *(const bf16x8*)(lb + s1off);
      int code = codeB + s * 128 + t * 16;
#pragma unroll
      for (int f = 0; f < 2; ++f) {
        f32x4 acc = {0.f, 0.f, 0.f, 0.f};
        acc = __builtin_amdgcn_mfma_f32_16x16x32_bf16(A0[f], b0, acc, 0, 0, 0);
        acc = __builtin_amdgcn_mfma_f32_16x16x32_bf16(A1[f], b1, acc, 0, 0, 0);
        float dmax = fmaxf(fmaxf(acc[0] - th[f][0], acc[1] - th[f][1]),
                           fmaxf(acc[2] - th[f][2], acc[3] - th[f][3]));
        if (dmax >= 0.f) {
#pragma unroll
          for (int r = 0; r < 4; ++r) {
            if (acc[r] >= th[f][r]) {
              int tok = tokBase + f * 16 + quad * 4 + r;
              int pos = atomicAdd(&g_candcnt[tok], 1);
              if (pos < CAP) g_cand[tok * CAP + pos] = code;
            }
          }
        }
      }
    }
    __syncthreads();
    p ^= 1;
  }
}

// k_scan: build worklist of flagged tokens (cnt >= 2). LDS flags + thread-0 serial
// exclusive scan (256 adds, trivial at 64 blocks) -> ONE atomicAdd per block.
__global__ __launch_bounds__(256) void k_scan() {
  __shared__ int flags[256];
  __shared__ int sbase;
  int tid = threadIdx.x;
  int tok = blockIdx.x * 256 + tid;
  int flag = (g_candcnt[tok] >= 2) ? 1 : 0;
  flags[tid] = flag;
  __syncthreads();
  if (tid == 0) {
    int run = 0;
    for (int i = 0; i < 256; ++i) {
      int f = flags[i];
      flags[i] = run;  // exclusive prefix
      run += f;
    }
    sbase = atomicAdd(&g_wln, run);
  }
  __syncthreads();
  if (flag) g_wl[sbase + flags[tid]] = tok;
}

// k_arb: resolve flagged tokens. 256 blocks x 4 waves = 1024 waves STRIDE the worklist
// (load-balanced, zero atomics). Per candidate: lane j computes qc_j = b_j + sum_k W[j,k]cb_k
// in fp64 via 4 independent chains (depth ~16 fma); WT layout [k][j] -> lane-stride-1 LDS
// reads (conflict-free). Score (z.qc)/||qc|| (monotone to ref), tie -> smallest code.
// Winner written to g_cand[tok*CAP]. Overflow (cnt>CAP): full fp64 scan (never fires).
__global__ __launch_bounds__(256) void k_arb(const float* __restrict__ z,
                                             const float* __restrict__ cb,
                                             const float* __restrict__ pw,
                                             const float* __restrict__ pb) {
  __shared__ double WT[64 * 65];  // WT[k*65+j] = W[j][k]
  __shared__ float cbl[4][64];
  int tid = threadIdx.x;
  int wave = tid >> 6, lane = tid & 63;
  for (int e = tid; e < 4096; e += 256) {
    int j = e >> 6, k = e & 63;
    WT[k * 65 + j] = (double)pw[e];
  }
  __syncthreads();

  int wln = g_wln;
  double bj = (double)pb[lane];
  int gwave = blockIdx.x * 4 + wave;

  for (int e = gwave; e < wln; e += 1024) {
    int tok = g_wl[e];
    int cnt = g_candcnt[tok];
    double zj = (double)z[(size_t)tok * 64 + lane];
    double best = -1.0e300;
    int bi = 0x7FFFFFFF;
    int lim = (cnt <= CAP) ? cnt : 0;
    for (int c = 0; c < lim; ++c) {
      int code = g_cand[tok * CAP + c];
      cbl[wave][lane] = cb[(size_t)code * 64 + lane];
      double s0 = 0.0, s1 = 0.0, s2 = 0.0, s3 = 0.0;
#pragma unroll
      for (int kk = 0; kk < 16; ++kk) {
        s0 = fma(WT[kk * 65 + lane], (double)cbl[wave][kk], s0);
        s1 = fma(WT[(kk + 16) * 65 + lane], (double)cbl[wave][kk + 16], s1);
        s2 = fma(WT[(kk + 32) * 65 + lane], (double)cbl[wave][kk + 32], s2);
        s3 = fma(WT[(kk + 48) * 65 + lane], (double)cbl[wave][kk + 48], s3);
      }
      double qc = ((s0 + s1) + (s2 + s3)) + bj;
      double s = zj * qc, n2 = qc * qc;
#pragma unroll
      for (int o = 32; o > 0; o >>= 1) {
        s += __shfl_xor(s, o, 64);
        n2 += __shfl_xor(n2, o, 64);
      }
      double key = s / fmax(sqrt(n2), 1e-12);
      if (key > best || (key == best && code < bi)) { best = key; bi = code; }
    }
    if (cnt > CAP) {  // correctness insurance; empirically never (max cnt seen <= 8 at r8)
      for (int code = 0; code < NCODES; ++code) {
        cbl[wave][lane] = cb[(size_t)code * 64 + lane];
        double s0 = 0.0, s1 = 0.0, s2 = 0.0, s3 = 0.0;
#pragma unroll
        for (int kk = 0; kk < 16; ++kk) {
          s0 = fma(WT[kk * 65 + lane], (double)cbl[wave][kk], s0);
          s1 = fma(WT[(kk + 16) * 65 + lane], (double)cbl[wave][kk + 16], s1);
          s2 = fma(WT[(kk + 32) * 65 + lane], (double)cbl[wave][kk + 32], s2);
          s3 = fma(WT[(kk + 48) * 65 + lane], (double)cbl[wave][kk + 48], s3);
        }
        double qc = ((s0 + s1) + (s2 + s3)) + bj;
        double s = zj * qc, n2 = qc * qc;
#pragma unroll
        for (int o = 32; o > 0; o >>= 1) {
          s += __shfl_xor(s, o, 64);
          n2 += __shfl_xor(n2, o, 64);
        }
        double key = s / fmax(sqrt(n2), 1e-12);
        if (key > best || (key == best && code < bi)) { best = key; bi = code; }
      }
    }
    if (lane == 0) g_cand[tok * CAP] = bi;
  }
}

// k_out: gather + straight-through + idx + per-block loss partial (plain stores only).
// 512 blocks x 32 tokens; wave handles 8 tokens.
__global__ __launch_bounds__(256) void k_out(const float* __restrict__ z,
                                             float* __restrict__ out0,
                                             float* __restrict__ out2) {
  __shared__ float ws[4];
  int tid = threadIdx.x;
  int wave = tid >> 6, lane = tid & 63;
  int base = blockIdx.x * 32;
  float lsum = 0.f;
  for (int r = 0; r < 8; ++r) {
    int tok = base + wave * 8 + r;
    int idx = g_cand[tok * CAP];  // winner (k_arb wrote it for flagged; slot0 otherwise)
    float q = g_qcb[(size_t)idx * 64 + lane];
    float zv = z[(size_t)tok * 64 + lane];
    float d = q - zv;
    out0[(size_t)tok * 64 + lane] = zv + d;  // z + (q - z), ref op order
    lsum = fmaf(d, d, lsum);
    if (lane == 0) out2[tok] = (float)idx;
  }
  float tot = wave_sum64(lsum);
  if (lane == 0) ws[wave] = tot;
  __syncthreads();
  if (tid == 0) g_partial[blockIdx.x] = ((ws[0] + ws[1]) + (ws[2] + ws[3]));
}

// k_loss: one wave sums the 512 partials in fixed order -> out1.
__global__ void k_loss(float* __restrict__ out1) {
  int lane = threadIdx.x;
  float s = 0.f;
#pragma unroll
  for (int i = 0; i < 8; ++i) s += g_partial[lane + 64 * i];
  s = wave_sum64(s);
  if (lane == 0) out1[0] = 1.25f * s / 1048576.0f;  // commitment == codebook numerically
}

extern "C" void kernel_launch(void* const* d_in, const int* in_sizes, int n_in,
                              void* d_out, int out_size, void* d_ws, size_t ws_size,
                              hipStream_t stream) {
  const float* z = (const float*)d_in[0];
  const float* cb = (const float*)d_in[1];
  const float* pw = (const float*)d_in[2];
  const float* pb = (const float*)d_in[3];
  // d_in[4] (scale) unused: argmin invariant to positive scale

  float* out0 = (float*)d_out;
  float* out1 = out0 + (size_t)NTOK * DIM;
  float* out2 = out1 + 1;

  hipLaunchKernelGGL(k_prep, dim3(512), dim3(256), 0, stream, cb, pw, pb, z);
  hipLaunchKernelGGL(k_mfma1, dim3(1024), dim3(256), 0, stream);
  hipLaunchKernelGGL(k_mfma2, dim3(1024), dim3(256), 0, stream);
  hipLaunchKernelGGL(k_scan, dim3(64), dim3(256), 0, stream);
  hipLaunchKernelGGL(k_arb, dim3(256), dim3(256), 0, stream, z, cb, pw, pb);
  hipLaunchKernelGGL(k_out, dim3(512), dim3(256), 0, stream, z, out0, out2);
  hipLaunchKernelGGL(k_loss, dim3(1), dim3(64), 0, stream, out1);
}